// Round 8
// baseline (381.953 us; speedup 1.0000x reference)
//
#include <hip/hip_runtime.h>

#define D 128   // feature dim
#define H 64    // hidden dim of classifier

// ---------- bf16 helpers (bit-level, RNE) ----------

__device__ __forceinline__ unsigned int bf16_rne(float f) {
    unsigned int u = __float_as_uint(f);
    u += 0x7fffu + ((u >> 16) & 1u);
    return u >> 16;
}
__device__ __forceinline__ unsigned int pack_bf16(float a, float b) {
    return bf16_rne(a) | (bf16_rne(b) << 16);
}
__device__ __forceinline__ float bf16_lo(unsigned int u) { return __uint_as_float(u << 16); }
__device__ __forceinline__ float bf16_hi(unsigned int u) { return __uint_as_float(u & 0xffff0000u); }

// ---------- FAT: gemm layer-1 ∥ CSR pass1, INTERLEAVED by blockIdx%3 ----------
// b%3==1 -> gemm block (id b/3); else pass1 block (2 edges/thread, int2 loads).
// Interleaving keeps pass1 at ~2/3 residency for the whole kernel (r7's segregated
// ranges filled all CUs with gemm first and starved the latency-bound atomic pass).

static __global__ __launch_bounds__(256) void fat1_k(
        const float* __restrict__ x, const float* __restrict__ W,
        unsigned int* __restrict__ hb, int n, int gemm_blocks,
        const int* __restrict__ ei, int E,
        int* __restrict__ cnt, int* __restrict__ rank) {
    __shared__ float Ws[32 * D];     // 16 KB
    __shared__ float xT[32 * 64];    //  8 KB
    const int tid = threadIdx.x;
    const int b = blockIdx.x;
    if (b % 3 != 1) {                // ---- pass1: 2 edges/thread ----
        int pid = 2 * (b / 3) + ((b % 3) == 0 ? 0 : 1);
        int e0 = pid * 512 + tid * 2;
        if (e0 + 1 < E) {
            int2 d2 = *(const int2*)&ei[E + e0];   // E even -> aligned
            int r0 = atomicAdd(&cnt[d2.x], 1);
            int r1 = atomicAdd(&cnt[d2.y], 1);
            *(int2*)&rank[e0] = make_int2(r0, r1);
        } else if (e0 < E) {
            rank[e0] = atomicAdd(&cnt[ei[E + e0]], 1);
        }
        return;
    }
    const int g = b / 3;
    if (g >= gemm_blocks) return;
    // ---- gemm1 (r5 structure, unscaled epilogue) ----
    const int row0 = g * 64;
    const int tx = tid & 31;
    const int ty = tid >> 5;
    const int sr = tid & 63;
    const int sk = (tid >> 6) * 4;
    const int gr = row0 + sr;

    float acc[8][4];
#pragma unroll
    for (int r = 0; r < 8; r++)
#pragma unroll
        for (int c = 0; c < 4; c++) acc[r][c] = 0.f;

    for (int kc = 0; kc < D; kc += 32) {
        float4 wreg[4];
#pragma unroll
        for (int i = 0; i < 4; i++)
            wreg[i] = ((const float4*)(W + kc * D))[tid + 256 * i];
        float4 v0 = make_float4(0.f, 0.f, 0.f, 0.f), v1 = v0;
        if (gr < n) {
            v0 = *(const float4*)&x[(size_t)gr * D + kc + sk];
            v1 = *(const float4*)&x[(size_t)gr * D + kc + sk + 16];
        }
        __syncthreads();
#pragma unroll
        for (int i = 0; i < 4; i++)
            ((float4*)Ws)[tid + 256 * i] = wreg[i];
        xT[(sk + 0) * 64 + sr] = v0.x;
        xT[(sk + 1) * 64 + sr] = v0.y;
        xT[(sk + 2) * 64 + sr] = v0.z;
        xT[(sk + 3) * 64 + sr] = v0.w;
        xT[(sk + 16) * 64 + sr] = v1.x;
        xT[(sk + 17) * 64 + sr] = v1.y;
        xT[(sk + 18) * 64 + sr] = v1.z;
        xT[(sk + 19) * 64 + sr] = v1.w;
        __syncthreads();
#pragma unroll 8
        for (int k = 0; k < 32; k++) {
            float4 w  = *(const float4*)&Ws[k * D + tx * 4];
            float4 xa = *(const float4*)&xT[k * 64 + ty * 8];
            float4 xb = *(const float4*)&xT[k * 64 + ty * 8 + 4];
            acc[0][0] = fmaf(xa.x, w.x, acc[0][0]); acc[0][1] = fmaf(xa.x, w.y, acc[0][1]);
            acc[0][2] = fmaf(xa.x, w.z, acc[0][2]); acc[0][3] = fmaf(xa.x, w.w, acc[0][3]);
            acc[1][0] = fmaf(xa.y, w.x, acc[1][0]); acc[1][1] = fmaf(xa.y, w.y, acc[1][1]);
            acc[1][2] = fmaf(xa.y, w.z, acc[1][2]); acc[1][3] = fmaf(xa.y, w.w, acc[1][3]);
            acc[2][0] = fmaf(xa.z, w.x, acc[2][0]); acc[2][1] = fmaf(xa.z, w.y, acc[2][1]);
            acc[2][2] = fmaf(xa.z, w.z, acc[2][2]); acc[2][3] = fmaf(xa.z, w.w, acc[2][3]);
            acc[3][0] = fmaf(xa.w, w.x, acc[3][0]); acc[3][1] = fmaf(xa.w, w.y, acc[3][1]);
            acc[3][2] = fmaf(xa.w, w.z, acc[3][2]); acc[3][3] = fmaf(xa.w, w.w, acc[3][3]);
            acc[4][0] = fmaf(xb.x, w.x, acc[4][0]); acc[4][1] = fmaf(xb.x, w.y, acc[4][1]);
            acc[4][2] = fmaf(xb.x, w.z, acc[4][2]); acc[4][3] = fmaf(xb.x, w.w, acc[4][3]);
            acc[5][0] = fmaf(xb.y, w.x, acc[5][0]); acc[5][1] = fmaf(xb.y, w.y, acc[5][1]);
            acc[5][2] = fmaf(xb.y, w.z, acc[5][2]); acc[5][3] = fmaf(xb.y, w.w, acc[5][3]);
            acc[6][0] = fmaf(xb.z, w.x, acc[6][0]); acc[6][1] = fmaf(xb.z, w.y, acc[6][1]);
            acc[6][2] = fmaf(xb.z, w.z, acc[6][2]); acc[6][3] = fmaf(xb.z, w.w, acc[6][3]);
            acc[7][0] = fmaf(xb.w, w.x, acc[7][0]); acc[7][1] = fmaf(xb.w, w.y, acc[7][1]);
            acc[7][2] = fmaf(xb.w, w.z, acc[7][2]); acc[7][3] = fmaf(xb.w, w.w, acc[7][3]);
        }
    }
#pragma unroll
    for (int r = 0; r < 8; r++) {
        int grr = row0 + ty * 8 + r;
        if (grr < n) {
            uint2 p;
            p.x = pack_bf16(acc[r][0], acc[r][1]);
            p.y = pack_bf16(acc[r][2], acc[r][3]);
            *(uint2*)&hb[(size_t)grr * (D / 2) + tx * 2] = p;
        }
    }
}

// ---------- Single-dispatch exclusive scan (decoupled lookback) + dinv ----------
// state[b] = (value << 2) | flag; flag: 1 = block aggregate, 2 = inclusive prefix.
// Values <= E = 800k so <<2 fits int. state must be zeroed before launch.
// 196 blocks -> all co-resident, lookback spin cannot deadlock.

static __global__ __launch_bounds__(256) void scan_k(
        const int* __restrict__ cnt, int n, int* __restrict__ state,
        int* __restrict__ rowptr, float* __restrict__ dinv) {
    __shared__ int s[256];
    __shared__ int sprefix;
    const int b = blockIdx.x;
    const int i = b * 256 + threadIdx.x;
    int v = (i < n) ? cnt[i] : 0;
    if (i < n) dinv[i] = rsqrtf((float)v + 1.0f);   // +1 self loop
    s[threadIdx.x] = v;
    __syncthreads();
    for (int off = 1; off < 256; off <<= 1) {        // inclusive Hillis-Steele
        int t = ((int)threadIdx.x >= off) ? s[threadIdx.x - off] : 0;
        __syncthreads();
        s[threadIdx.x] += t;
        __syncthreads();
    }
    int incl = s[threadIdx.x];
    int total = s[255];
    if (threadIdx.x == 0) {
        if (b == 0) {
            atomicExch(&state[0], (total << 2) | 2);
            sprefix = 0;
        } else {
            atomicExch(&state[b], (total << 2) | 1);
            int run = 0;
            for (int j = b - 1; j >= 0; j--) {
                int p;
                do { p = atomicAdd(&state[j], 0); } while ((p & 3) == 0);
                run += (p >> 2);
                if ((p & 3) == 2) break;
            }
            atomicExch(&state[b], ((run + total) << 2) | 2);
            sprefix = run;
        }
    }
    __syncthreads();
    int pre = sprefix;
    if (i < n) {
        rowptr[i] = pre + incl - v;
        if (i == n - 1) rowptr[n] = pre + incl;
    }
}

// ---------- pass2: no-atomic scatter, 2 edges/thread ----------

static __global__ void pass2_k(const int* __restrict__ ei, int E,
                               const int* __restrict__ rank,
                               const int* __restrict__ rowptr,
                               int* __restrict__ csr_src) {
    int e0 = (blockIdx.x * blockDim.x + threadIdx.x) * 2;
    if (e0 + 1 < E) {
        int2 s2 = *(const int2*)&ei[e0];
        int2 d2 = *(const int2*)&ei[E + e0];
        int2 r2 = *(const int2*)&rank[e0];
        csr_src[rowptr[d2.x] + r2.x] = s2.x;
        csr_src[rowptr[d2.y] + r2.y] = s2.y;
    } else if (e0 < E) {
        csr_src[rowptr[ei[E + e0]] + rank[e0]] = ei[e0];
    }
}

// ---------- Aggregation + bias + relu ----------
// 1 wave per node; node in SGPR (readfirstlane) -> rowptr/csr loads are scalar;
// ceil(deg/8) batches of 8 clamped+predicated gathers, 8 outstanding loads/wave.

template <bool SCALED>
static __global__ __launch_bounds__(256) void agg_k(const unsigned int* __restrict__ hb,
                                                    const float* __restrict__ dinv,
                                                    const int* __restrict__ rowptr,
                                                    const int* __restrict__ csr,
                                                    const float* __restrict__ b,
                                                    unsigned int* __restrict__ outp, int n) {
    int node = blockIdx.x * 4 + (threadIdx.x >> 6);
    node = __builtin_amdgcn_readfirstlane(node);
    if (node >= n) return;
    const int lane = threadIdx.x & 63;
    const int beg = rowptr[node], end = rowptr[node + 1];
    float a0 = 0.f, a1 = 0.f;
    for (int base = beg; base < end; base += 8) {
        int s[8];
        float w[8];
#pragma unroll
        for (int i = 0; i < 8; i++) {
            int ee = base + i;
            int ec = (ee < end) ? ee : end - 1;
            s[i] = csr[ec];
        }
#pragma unroll
        for (int i = 0; i < 8; i++) {
            bool live = (base + i) < end;
            if constexpr (SCALED) w[i] = live ? 1.0f : 0.0f;
            else                  w[i] = live ? dinv[s[i]] : 0.0f;
        }
#pragma unroll
        for (int i = 0; i < 8; i++) {
            unsigned int v = hb[(size_t)s[i] * 64 + lane];
            a0 = fmaf(w[i], bf16_lo(v), a0);
            a1 = fmaf(w[i], bf16_hi(v), a1);
        }
    }
    float di = dinv[node];
    unsigned int hv = hb[(size_t)node * 64 + lane];   // self loop
    if constexpr (SCALED) { a0 += bf16_lo(hv);              a1 += bf16_hi(hv); }
    else                  { a0 = fmaf(di, bf16_lo(hv), a0); a1 = fmaf(di, bf16_hi(hv), a1); }
    float2 bb = *(const float2*)&b[lane * 2];
    float o0 = fmaxf(fmaf(di, a0, bb.x), 0.f);
    float o1 = fmaxf(fmaf(di, a1, bb.y), 0.f);
    outp[(size_t)node * 64 + lane] = pack_bf16(o0, o1);
}

// ---------- GEMM layers 2/3: hb = bf16( dinv[row] * (xpacked @ W) ) ----------

static __global__ __launch_bounds__(256) void gemm_k(const unsigned int* __restrict__ xp,
                                                     const float* __restrict__ W,
                                                     const float* __restrict__ dinv,
                                                     unsigned int* __restrict__ hb, int n) {
    __shared__ float Ws[32 * D];
    __shared__ float xT[32 * 64];
    const int tid = threadIdx.x;
    const int row0 = blockIdx.x * 64;
    const int tx = tid & 31;
    const int ty = tid >> 5;
    const int sr = tid & 63;
    const int sk = (tid >> 6) * 4;
    const int gr = row0 + sr;

    float acc[8][4];
#pragma unroll
    for (int r = 0; r < 8; r++)
#pragma unroll
        for (int c = 0; c < 4; c++) acc[r][c] = 0.f;

    for (int kc = 0; kc < D; kc += 32) {
        float4 wreg[4];
#pragma unroll
        for (int i = 0; i < 4; i++)
            wreg[i] = ((const float4*)(W + kc * D))[tid + 256 * i];
        float4 v0 = make_float4(0.f, 0.f, 0.f, 0.f), v1 = v0;
        if (gr < n) {
            const uint2* x2 = (const uint2*)xp;
            uint2 u0 = x2[(size_t)gr * 32 + ((kc + sk) >> 2)];
            uint2 u1 = x2[(size_t)gr * 32 + ((kc + sk + 16) >> 2)];
            v0 = make_float4(bf16_lo(u0.x), bf16_hi(u0.x), bf16_lo(u0.y), bf16_hi(u0.y));
            v1 = make_float4(bf16_lo(u1.x), bf16_hi(u1.x), bf16_lo(u1.y), bf16_hi(u1.y));
        }
        __syncthreads();
#pragma unroll
        for (int i = 0; i < 4; i++)
            ((float4*)Ws)[tid + 256 * i] = wreg[i];
        xT[(sk + 0) * 64 + sr] = v0.x;
        xT[(sk + 1) * 64 + sr] = v0.y;
        xT[(sk + 2) * 64 + sr] = v0.z;
        xT[(sk + 3) * 64 + sr] = v0.w;
        xT[(sk + 16) * 64 + sr] = v1.x;
        xT[(sk + 17) * 64 + sr] = v1.y;
        xT[(sk + 18) * 64 + sr] = v1.z;
        xT[(sk + 19) * 64 + sr] = v1.w;
        __syncthreads();
#pragma unroll 8
        for (int k = 0; k < 32; k++) {
            float4 w  = *(const float4*)&Ws[k * D + tx * 4];
            float4 xa = *(const float4*)&xT[k * 64 + ty * 8];
            float4 xb = *(const float4*)&xT[k * 64 + ty * 8 + 4];
            acc[0][0] = fmaf(xa.x, w.x, acc[0][0]); acc[0][1] = fmaf(xa.x, w.y, acc[0][1]);
            acc[0][2] = fmaf(xa.x, w.z, acc[0][2]); acc[0][3] = fmaf(xa.x, w.w, acc[0][3]);
            acc[1][0] = fmaf(xa.y, w.x, acc[1][0]); acc[1][1] = fmaf(xa.y, w.y, acc[1][1]);
            acc[1][2] = fmaf(xa.y, w.z, acc[1][2]); acc[1][3] = fmaf(xa.y, w.w, acc[1][3]);
            acc[2][0] = fmaf(xa.z, w.x, acc[2][0]); acc[2][1] = fmaf(xa.z, w.y, acc[2][1]);
            acc[2][2] = fmaf(xa.z, w.z, acc[2][2]); acc[2][3] = fmaf(xa.z, w.w, acc[2][3]);
            acc[3][0] = fmaf(xa.w, w.x, acc[3][0]); acc[3][1] = fmaf(xa.w, w.y, acc[3][1]);
            acc[3][2] = fmaf(xa.w, w.z, acc[3][2]); acc[3][3] = fmaf(xa.w, w.w, acc[3][3]);
            acc[4][0] = fmaf(xb.x, w.x, acc[4][0]); acc[4][1] = fmaf(xb.x, w.y, acc[4][1]);
            acc[4][2] = fmaf(xb.x, w.z, acc[4][2]); acc[4][3] = fmaf(xb.x, w.w, acc[4][3]);
            acc[5][0] = fmaf(xb.y, w.x, acc[5][0]); acc[5][1] = fmaf(xb.y, w.y, acc[5][1]);
            acc[5][2] = fmaf(xb.y, w.z, acc[5][2]); acc[5][3] = fmaf(xb.y, w.w, acc[5][3]);
            acc[6][0] = fmaf(xb.z, w.x, acc[6][0]); acc[6][1] = fmaf(xb.z, w.y, acc[6][1]);
            acc[6][2] = fmaf(xb.z, w.z, acc[6][2]); acc[6][3] = fmaf(xb.z, w.w, acc[6][3]);
            acc[7][0] = fmaf(xb.w, w.x, acc[7][0]); acc[7][1] = fmaf(xb.w, w.y, acc[7][1]);
            acc[7][2] = fmaf(xb.w, w.z, acc[7][2]); acc[7][3] = fmaf(xb.w, w.w, acc[7][3]);
        }
    }
#pragma unroll
    for (int r = 0; r < 8; r++) {
        int grr = row0 + ty * 8 + r;
        if (grr < n) {
            float dr = dinv[grr];
            uint2 p;
            p.x = pack_bf16(acc[r][0] * dr, acc[r][1] * dr);
            p.y = pack_bf16(acc[r][2] * dr, acc[r][3] * dr);
            *(uint2*)&hb[(size_t)grr * (D / 2) + tx * 2] = p;
        }
    }
}

// ---------- Fused mean-pool + classifier ----------

static __global__ __launch_bounds__(256) void poolcls_k(const unsigned int* __restrict__ xp,
                                                        const int* __restrict__ batch, int n,
                                                        const float* __restrict__ Wc,
                                                        const float* __restrict__ bc,
                                                        const float* __restrict__ Wo,
                                                        const float* __restrict__ bo,
                                                        float* __restrict__ out) {
    int g = blockIdx.x;
    int f = threadIdx.x & 127;
    int half = threadIdx.x >> 7;
    int lo = 0, hi = n;
    while (lo < hi) { int m = (lo + hi) >> 1; if (batch[m] < g) lo = m + 1; else hi = m; }
    int start = lo;
    hi = n;
    while (lo < hi) { int m = (lo + hi) >> 1; if (batch[m] < g + 1) lo = m + 1; else hi = m; }
    int end = lo;
    float s = 0.f;
    const int ui = f >> 1;
    const bool hif = f & 1;
    for (int r = start + half; r < end; r += 2) {
        unsigned int u = xp[(size_t)r * 64 + ui];
        s += hif ? bf16_hi(u) : bf16_lo(u);
    }
    __shared__ float red[256];
    __shared__ float pooled[D];
    red[threadIdx.x] = s;
    __syncthreads();
    if (half == 0) {
        float tot = red[f] + red[f + 128];
        float c = (float)(end - start);
        pooled[f] = tot / fmaxf(c, 1.0f);
    }
    __syncthreads();
    int t = threadIdx.x;
    if (t < H) {
        float z = bc[t];
        for (int k = 0; k < D; k++) z = fmaf(pooled[k], Wc[k * H + t], z);
        z = fmaxf(z, 0.f);
        float v = z * Wo[t];
        for (int off = 32; off > 0; off >>= 1) v += __shfl_down(v, off);
        if (t == 0) out[g] = v + bo[0];
    }
}

// ---------- Orchestration ----------

extern "C" void kernel_launch(void* const* d_in, const int* in_sizes, int n_in,
                              void* d_out, int out_size, void* d_ws, size_t ws_size,
                              hipStream_t stream) {
    const float* x     = (const float*)d_in[0];
    const int*   ei    = (const int*)d_in[1];
    const int*   batch = (const int*)d_in[2];
    const float* W1 = (const float*)d_in[3];
    const float* b1 = (const float*)d_in[4];
    const float* W2 = (const float*)d_in[5];
    const float* b2 = (const float*)d_in[6];
    const float* W3 = (const float*)d_in[7];
    const float* b3 = (const float*)d_in[8];
    const float* Wc = (const float*)d_in[9];
    const float* bc = (const float*)d_in[10];
    const float* Wo = (const float*)d_in[11];
    const float* bo = (const float*)d_in[12];

    const int n = in_sizes[0] / D;
    const int E = in_sizes[1] / 2;
    const int G = out_size;

    char* ws = (char*)d_ws;
    size_t off = 0;
    auto alloc = [&](size_t bytes) -> void* {
        void* p = ws + off;
        off = (off + bytes + 255) & ~(size_t)255;
        return p;
    };
    // cnt and scan-state share one zeroing memset (contiguous alloc)
    int*   cnt     = (int*)alloc((size_t)n * 4 + 4096);
    int*   state   = cnt + n;                       // scan lookback state (<= 1024 ints)
    int*   rowptr  = (int*)alloc((size_t)(n + 1) * 4);
    float* dinv    = (float*)alloc((size_t)n * 4);
    int*   rank    = (int*)alloc((size_t)E * 4);
    int*   csr_src = (int*)alloc((size_t)E * 4);
    unsigned int* hb = (unsigned int*)alloc((size_t)n * (D / 2) * 4);  // packed bf16 gemm out
    unsigned int* xb = (unsigned int*)alloc((size_t)n * (D / 2) * 4);  // packed bf16 agg out
    (void)ws_size; (void)n_in;

    hipMemsetAsync(cnt, 0, (size_t)n * 4 + 4096, stream);

    const int nb = (n + 255) / 256;
    const int gemm_blocks = (n + 63) / 64;
    const int p1_blocks   = (E + 511) / 512;        // 2 edges/thread
    const int p2_blocks   = (E + 511) / 512;
    const int agg_blocks  = (n + 3) / 4;
    // fat1 grid: triples [pass1, gemm, pass1]; enough triples for both roles
    int triples = gemm_blocks > (p1_blocks + 1) / 2 ? gemm_blocks : (p1_blocks + 1) / 2;

    fat1_k<<<3 * triples, 256, 0, stream>>>(x, W1, hb, n, gemm_blocks, ei, E, cnt, rank);
    scan_k<<<nb, 256, 0, stream>>>(cnt, n, state, rowptr, dinv);
    pass2_k<<<p2_blocks, 256, 0, stream>>>(ei, E, rank, rowptr, csr_src);

    // layer 1: per-edge dinv[s] (hb unscaled)
    agg_k<false><<<agg_blocks, 256, 0, stream>>>(hb, dinv, rowptr, csr_src, b1, xb, n);
    // layers 2,3: pre-scaled hb
    gemm_k<<<gemm_blocks, 256, 0, stream>>>(xb, W2, dinv, hb, n);
    agg_k<true><<<agg_blocks, 256, 0, stream>>>(hb, dinv, rowptr, csr_src, b2, xb, n);
    gemm_k<<<gemm_blocks, 256, 0, stream>>>(xb, W3, dinv, hb, n);
    agg_k<true><<<agg_blocks, 256, 0, stream>>>(hb, dinv, rowptr, csr_src, b3, xb, n);

    poolcls_k<<<G, 256, 0, stream>>>(xb, batch, n, Wc, bc, Wo, bo, (float*)d_out);
}

// Round 9
// 366.897 us; speedup vs baseline: 1.0410x; 1.0410x over previous
//
#include <hip/hip_runtime.h>

#define D 128   // feature dim
#define H 64    // hidden dim of classifier

// ---------- bf16 helpers (bit-level, RNE) ----------

__device__ __forceinline__ unsigned int bf16_rne(float f) {
    unsigned int u = __float_as_uint(f);
    u += 0x7fffu + ((u >> 16) & 1u);
    return u >> 16;
}
__device__ __forceinline__ unsigned int pack_bf16(float a, float b) {
    return bf16_rne(a) | (bf16_rne(b) << 16);
}
__device__ __forceinline__ float bf16_lo(unsigned int u) { return __uint_as_float(u << 16); }
__device__ __forceinline__ float bf16_hi(unsigned int u) { return __uint_as_float(u & 0xffff0000u); }

// ---------- FAT: gemm layer-1 (fp32 x @ W1 -> UNSCALED bf16) ∥ CSR pass1 ----------
// r7 structure (segregated ranges): gemm blocks first, pass1 blocks fill remaining
// slots -> measured ~10 us of real overlap. (r8's %3 interleave regressed; reverted.)

static __global__ __launch_bounds__(256) void fat1_k(
        const float* __restrict__ x, const float* __restrict__ W,
        unsigned int* __restrict__ hb, int n, int gb,
        const int* __restrict__ ei, int E,
        int* __restrict__ cnt, int* __restrict__ rank) {
    __shared__ float Ws[32 * D];     // 16 KB
    __shared__ float xT[32 * 64];    //  8 KB
    const int tid = threadIdx.x;
    if ((int)blockIdx.x >= gb) {     // ---- pass1 ----
        int e = ((int)blockIdx.x - gb) * 256 + tid;
        if (e < E) rank[e] = atomicAdd(&cnt[ei[E + e]], 1);
        return;
    }
    // ---- gemm1 ----
    const int row0 = blockIdx.x * 64;
    const int tx = tid & 31;
    const int ty = tid >> 5;
    const int sr = tid & 63;
    const int sk = (tid >> 6) * 4;
    const int gr = row0 + sr;

    float acc[8][4];
#pragma unroll
    for (int r = 0; r < 8; r++)
#pragma unroll
        for (int c = 0; c < 4; c++) acc[r][c] = 0.f;

    for (int kc = 0; kc < D; kc += 32) {
        float4 wreg[4];
#pragma unroll
        for (int i = 0; i < 4; i++)
            wreg[i] = ((const float4*)(W + kc * D))[tid + 256 * i];
        float4 v0 = make_float4(0.f, 0.f, 0.f, 0.f), v1 = v0;
        if (gr < n) {
            v0 = *(const float4*)&x[(size_t)gr * D + kc + sk];
            v1 = *(const float4*)&x[(size_t)gr * D + kc + sk + 16];
        }
        __syncthreads();
#pragma unroll
        for (int i = 0; i < 4; i++)
            ((float4*)Ws)[tid + 256 * i] = wreg[i];
        xT[(sk + 0) * 64 + sr] = v0.x;
        xT[(sk + 1) * 64 + sr] = v0.y;
        xT[(sk + 2) * 64 + sr] = v0.z;
        xT[(sk + 3) * 64 + sr] = v0.w;
        xT[(sk + 16) * 64 + sr] = v1.x;
        xT[(sk + 17) * 64 + sr] = v1.y;
        xT[(sk + 18) * 64 + sr] = v1.z;
        xT[(sk + 19) * 64 + sr] = v1.w;
        __syncthreads();
#pragma unroll 8
        for (int k = 0; k < 32; k++) {
            float4 w  = *(const float4*)&Ws[k * D + tx * 4];
            float4 xa = *(const float4*)&xT[k * 64 + ty * 8];
            float4 xb = *(const float4*)&xT[k * 64 + ty * 8 + 4];
            acc[0][0] = fmaf(xa.x, w.x, acc[0][0]); acc[0][1] = fmaf(xa.x, w.y, acc[0][1]);
            acc[0][2] = fmaf(xa.x, w.z, acc[0][2]); acc[0][3] = fmaf(xa.x, w.w, acc[0][3]);
            acc[1][0] = fmaf(xa.y, w.x, acc[1][0]); acc[1][1] = fmaf(xa.y, w.y, acc[1][1]);
            acc[1][2] = fmaf(xa.y, w.z, acc[1][2]); acc[1][3] = fmaf(xa.y, w.w, acc[1][3]);
            acc[2][0] = fmaf(xa.z, w.x, acc[2][0]); acc[2][1] = fmaf(xa.z, w.y, acc[2][1]);
            acc[2][2] = fmaf(xa.z, w.z, acc[2][2]); acc[2][3] = fmaf(xa.z, w.w, acc[2][3]);
            acc[3][0] = fmaf(xa.w, w.x, acc[3][0]); acc[3][1] = fmaf(xa.w, w.y, acc[3][1]);
            acc[3][2] = fmaf(xa.w, w.z, acc[3][2]); acc[3][3] = fmaf(xa.w, w.w, acc[3][3]);
            acc[4][0] = fmaf(xb.x, w.x, acc[4][0]); acc[4][1] = fmaf(xb.x, w.y, acc[4][1]);
            acc[4][2] = fmaf(xb.x, w.z, acc[4][2]); acc[4][3] = fmaf(xb.x, w.w, acc[4][3]);
            acc[5][0] = fmaf(xb.y, w.x, acc[5][0]); acc[5][1] = fmaf(xb.y, w.y, acc[5][1]);
            acc[5][2] = fmaf(xb.y, w.z, acc[5][2]); acc[5][3] = fmaf(xb.y, w.w, acc[5][3]);
            acc[6][0] = fmaf(xb.z, w.x, acc[6][0]); acc[6][1] = fmaf(xb.z, w.y, acc[6][1]);
            acc[6][2] = fmaf(xb.z, w.z, acc[6][2]); acc[6][3] = fmaf(xb.z, w.w, acc[6][3]);
            acc[7][0] = fmaf(xb.w, w.x, acc[7][0]); acc[7][1] = fmaf(xb.w, w.y, acc[7][1]);
            acc[7][2] = fmaf(xb.w, w.z, acc[7][2]); acc[7][3] = fmaf(xb.w, w.w, acc[7][3]);
        }
    }
#pragma unroll
    for (int r = 0; r < 8; r++) {
        int grr = row0 + ty * 8 + r;
        if (grr < n) {
            uint2 p;
            p.x = pack_bf16(acc[r][0], acc[r][1]);
            p.y = pack_bf16(acc[r][2], acc[r][3]);
            *(uint2*)&hb[(size_t)grr * (D / 2) + tx * 2] = p;
        }
    }
}

// ---------- Single-dispatch exclusive scan (decoupled lookback) + dinv ----------

static __global__ __launch_bounds__(256) void scan_k(
        const int* __restrict__ cnt, int n, int* __restrict__ state,
        int* __restrict__ rowptr, float* __restrict__ dinv) {
    __shared__ int s[256];
    __shared__ int sprefix;
    const int b = blockIdx.x;
    const int i = b * 256 + threadIdx.x;
    int v = (i < n) ? cnt[i] : 0;
    if (i < n) dinv[i] = rsqrtf((float)v + 1.0f);   // +1 self loop
    s[threadIdx.x] = v;
    __syncthreads();
    for (int off = 1; off < 256; off <<= 1) {
        int t = ((int)threadIdx.x >= off) ? s[threadIdx.x - off] : 0;
        __syncthreads();
        s[threadIdx.x] += t;
        __syncthreads();
    }
    int incl = s[threadIdx.x];
    int total = s[255];
    if (threadIdx.x == 0) {
        if (b == 0) {
            atomicExch(&state[0], (total << 2) | 2);
            sprefix = 0;
        } else {
            atomicExch(&state[b], (total << 2) | 1);
            int run = 0;
            for (int j = b - 1; j >= 0; j--) {
                int p;
                do { p = atomicAdd(&state[j], 0); } while ((p & 3) == 0);
                run += (p >> 2);
                if ((p & 3) == 2) break;
            }
            atomicExch(&state[b], ((run + total) << 2) | 2);
            sprefix = run;
        }
    }
    __syncthreads();
    int pre = sprefix;
    if (i < n) {
        rowptr[i] = pre + incl - v;
        if (i == n - 1) rowptr[n] = pre + incl;
    }
}

// ---------- pass2: no-atomic scatter, 2 edges/thread ----------

static __global__ void pass2_k(const int* __restrict__ ei, int E,
                               const int* __restrict__ rank,
                               const int* __restrict__ rowptr,
                               int* __restrict__ csr_src) {
    int e0 = (blockIdx.x * blockDim.x + threadIdx.x) * 2;
    if (e0 + 1 < E) {
        int2 s2 = *(const int2*)&ei[e0];
        int2 d2 = *(const int2*)&ei[E + e0];
        int2 r2 = *(const int2*)&rank[e0];
        csr_src[rowptr[d2.x] + r2.x] = s2.x;
        csr_src[rowptr[d2.y] + r2.y] = s2.y;
    } else if (e0 < E) {
        csr_src[rowptr[ei[E + e0]] + rank[e0]] = ei[e0];
    }
}

// ---------- Aggregation + bias + relu: 2 NODES PER WAVE ----------
// Half-wave per node (32 lanes x uint2 = 4 feats/lane, 256 B/edge unchanged);
// 8-batch per half -> 16 outstanding gathers/wave (2x r7 MLP), half the waves.
// Edge order per node identical to r7 -> bit-identical accumulation.
// Scalar path: rowptr/csr/dinv via s_load, one v_cndmask select on half.

template <bool SCALED>
static __global__ __launch_bounds__(256) void agg_k(const unsigned int* __restrict__ hb,
                                                    const float* __restrict__ dinv,
                                                    const int* __restrict__ rowptr,
                                                    const int* __restrict__ csr,
                                                    const float* __restrict__ b,
                                                    unsigned int* __restrict__ outp, int n) {
    int nodeA = blockIdx.x * 8 + ((threadIdx.x >> 6) << 1);
    nodeA = __builtin_amdgcn_readfirstlane(nodeA);
    if (nodeA >= n) return;
    const int nodeB = nodeA + 1;
    const bool hasB = nodeB < n;
    const int lane = threadIdx.x & 63;
    const int half = lane >> 5;        // 0 -> nodeA, 1 -> nodeB
    const int l = lane & 31;           // uint-pair index: feats 4l..4l+3

    const int begA = rowptr[nodeA];
    const int endA = rowptr[nodeA + 1];
    const int begB = hasB ? endA : 0;
    const int endB = hasB ? rowptr[nodeB + 1] : 0;
    const int safeA = (endA > begA) ? endA - 1 : 0;   // deg-0 guard: replay csr[0], w=0
    const int safeB = (endB > begB) ? endB - 1 : 0;
    const int degA = endA - begA, degB = endB - begB;
    int nbat = (degA > degB ? degA : degB);
    nbat = (nbat + 7) >> 3;

    const int myEnd = half ? endB : endA;
    float a0 = 0.f, a1 = 0.f, a2 = 0.f, a3 = 0.f;
    for (int t = 0; t < nbat; t++) {
        int s[8];
        float w[8];
#pragma unroll
        for (int i = 0; i < 8; i++) {
            int eA = begA + t * 8 + i; int ecA = (eA < endA) ? eA : safeA;
            int eB = begB + t * 8 + i; int ecB = (eB < endB) ? eB : safeB;
            int sA = csr[ecA];                 // scalar
            int sB = csr[ecB];                 // scalar
            s[i] = half ? sB : sA;             // cndmask
            bool live = (half ? eB : eA) < myEnd;
            if constexpr (SCALED) {
                w[i] = live ? 1.0f : 0.0f;
            } else {
                float dA = dinv[sA];           // scalar
                float dB = dinv[sB];           // scalar
                w[i] = live ? (half ? dB : dA) : 0.0f;
            }
        }
#pragma unroll
        for (int i = 0; i < 8; i++) {
            uint2 v = *(const uint2*)&hb[(size_t)s[i] * 64 + l * 2];
            a0 = fmaf(w[i], bf16_lo(v.x), a0);
            a1 = fmaf(w[i], bf16_hi(v.x), a1);
            a2 = fmaf(w[i], bf16_lo(v.y), a2);
            a3 = fmaf(w[i], bf16_hi(v.y), a3);
        }
    }
    const int node = half ? nodeB : nodeA;
    const float dA = dinv[nodeA];
    const float dB = hasB ? dinv[nodeB] : 0.f;
    const float di = half ? dB : dA;
    uint2 hv = *(const uint2*)&hb[(size_t)(hasB ? node : nodeA) * 64 + l * 2];  // self loop
    if constexpr (SCALED) {
        a0 += bf16_lo(hv.x); a1 += bf16_hi(hv.x);
        a2 += bf16_lo(hv.y); a3 += bf16_hi(hv.y);
    } else {
        a0 = fmaf(di, bf16_lo(hv.x), a0); a1 = fmaf(di, bf16_hi(hv.x), a1);
        a2 = fmaf(di, bf16_lo(hv.y), a2); a3 = fmaf(di, bf16_hi(hv.y), a3);
    }
    float4 bb = *(const float4*)&b[l * 4];
    float o0 = fmaxf(fmaf(di, a0, bb.x), 0.f);
    float o1 = fmaxf(fmaf(di, a1, bb.y), 0.f);
    float o2 = fmaxf(fmaf(di, a2, bb.z), 0.f);
    float o3 = fmaxf(fmaf(di, a3, bb.w), 0.f);
    if (half == 0 || hasB) {
        uint2 p;
        p.x = pack_bf16(o0, o1);
        p.y = pack_bf16(o2, o3);
        *(uint2*)&outp[(size_t)node * 64 + l * 2] = p;
    }
}

// ---------- GEMM layers 2/3: hb = bf16( dinv[row] * (xpacked @ W) ) ----------

static __global__ __launch_bounds__(256) void gemm_k(const unsigned int* __restrict__ xp,
                                                     const float* __restrict__ W,
                                                     const float* __restrict__ dinv,
                                                     unsigned int* __restrict__ hb, int n) {
    __shared__ float Ws[32 * D];
    __shared__ float xT[32 * 64];
    const int tid = threadIdx.x;
    const int row0 = blockIdx.x * 64;
    const int tx = tid & 31;
    const int ty = tid >> 5;
    const int sr = tid & 63;
    const int sk = (tid >> 6) * 4;
    const int gr = row0 + sr;

    float acc[8][4];
#pragma unroll
    for (int r = 0; r < 8; r++)
#pragma unroll
        for (int c = 0; c < 4; c++) acc[r][c] = 0.f;

    for (int kc = 0; kc < D; kc += 32) {
        float4 wreg[4];
#pragma unroll
        for (int i = 0; i < 4; i++)
            wreg[i] = ((const float4*)(W + kc * D))[tid + 256 * i];
        float4 v0 = make_float4(0.f, 0.f, 0.f, 0.f), v1 = v0;
        if (gr < n) {
            const uint2* x2 = (const uint2*)xp;
            uint2 u0 = x2[(size_t)gr * 32 + ((kc + sk) >> 2)];
            uint2 u1 = x2[(size_t)gr * 32 + ((kc + sk + 16) >> 2)];
            v0 = make_float4(bf16_lo(u0.x), bf16_hi(u0.x), bf16_lo(u0.y), bf16_hi(u0.y));
            v1 = make_float4(bf16_lo(u1.x), bf16_hi(u1.x), bf16_lo(u1.y), bf16_hi(u1.y));
        }
        __syncthreads();
#pragma unroll
        for (int i = 0; i < 4; i++)
            ((float4*)Ws)[tid + 256 * i] = wreg[i];
        xT[(sk + 0) * 64 + sr] = v0.x;
        xT[(sk + 1) * 64 + sr] = v0.y;
        xT[(sk + 2) * 64 + sr] = v0.z;
        xT[(sk + 3) * 64 + sr] = v0.w;
        xT[(sk + 16) * 64 + sr] = v1.x;
        xT[(sk + 17) * 64 + sr] = v1.y;
        xT[(sk + 18) * 64 + sr] = v1.z;
        xT[(sk + 19) * 64 + sr] = v1.w;
        __syncthreads();
#pragma unroll 8
        for (int k = 0; k < 32; k++) {
            float4 w  = *(const float4*)&Ws[k * D + tx * 4];
            float4 xa = *(const float4*)&xT[k * 64 + ty * 8];
            float4 xb = *(const float4*)&xT[k * 64 + ty * 8 + 4];
            acc[0][0] = fmaf(xa.x, w.x, acc[0][0]); acc[0][1] = fmaf(xa.x, w.y, acc[0][1]);
            acc[0][2] = fmaf(xa.x, w.z, acc[0][2]); acc[0][3] = fmaf(xa.x, w.w, acc[0][3]);
            acc[1][0] = fmaf(xa.y, w.x, acc[1][0]); acc[1][1] = fmaf(xa.y, w.y, acc[1][1]);
            acc[1][2] = fmaf(xa.y, w.z, acc[1][2]); acc[1][3] = fmaf(xa.y, w.w, acc[1][3]);
            acc[2][0] = fmaf(xa.z, w.x, acc[2][0]); acc[2][1] = fmaf(xa.z, w.y, acc[2][1]);
            acc[2][2] = fmaf(xa.z, w.z, acc[2][2]); acc[2][3] = fmaf(xa.z, w.w, acc[2][3]);
            acc[3][0] = fmaf(xa.w, w.x, acc[3][0]); acc[3][1] = fmaf(xa.w, w.y, acc[3][1]);
            acc[3][2] = fmaf(xa.w, w.z, acc[3][2]); acc[3][3] = fmaf(xa.w, w.w, acc[3][3]);
            acc[4][0] = fmaf(xb.x, w.x, acc[4][0]); acc[4][1] = fmaf(xb.x, w.y, acc[4][1]);
            acc[4][2] = fmaf(xb.x, w.z, acc[4][2]); acc[4][3] = fmaf(xb.x, w.w, acc[4][3]);
            acc[5][0] = fmaf(xb.y, w.x, acc[5][0]); acc[5][1] = fmaf(xb.y, w.y, acc[5][1]);
            acc[5][2] = fmaf(xb.y, w.z, acc[5][2]); acc[5][3] = fmaf(xb.y, w.w, acc[5][3]);
            acc[6][0] = fmaf(xb.z, w.x, acc[6][0]); acc[6][1] = fmaf(xb.z, w.y, acc[6][1]);
            acc[6][2] = fmaf(xb.z, w.z, acc[6][2]); acc[6][3] = fmaf(xb.z, w.w, acc[6][3]);
            acc[7][0] = fmaf(xb.w, w.x, acc[7][0]); acc[7][1] = fmaf(xb.w, w.y, acc[7][1]);
            acc[7][2] = fmaf(xb.w, w.z, acc[7][2]); acc[7][3] = fmaf(xb.w, w.w, acc[7][3]);
        }
    }
#pragma unroll
    for (int r = 0; r < 8; r++) {
        int grr = row0 + ty * 8 + r;
        if (grr < n) {
            float dr = dinv[grr];
            uint2 p;
            p.x = pack_bf16(acc[r][0] * dr, acc[r][1] * dr);
            p.y = pack_bf16(acc[r][2] * dr, acc[r][3] * dr);
            *(uint2*)&hb[(size_t)grr * (D / 2) + tx * 2] = p;
        }
    }
}

// ---------- Fused mean-pool + classifier ----------

static __global__ __launch_bounds__(256) void poolcls_k(const unsigned int* __restrict__ xp,
                                                        const int* __restrict__ batch, int n,
                                                        const float* __restrict__ Wc,
                                                        const float* __restrict__ bc,
                                                        const float* __restrict__ Wo,
                                                        const float* __restrict__ bo,
                                                        float* __restrict__ out) {
    int g = blockIdx.x;
    int f = threadIdx.x & 127;
    int half = threadIdx.x >> 7;
    int lo = 0, hi = n;
    while (lo < hi) { int m = (lo + hi) >> 1; if (batch[m] < g) lo = m + 1; else hi = m; }
    int start = lo;
    hi = n;
    while (lo < hi) { int m = (lo + hi) >> 1; if (batch[m] < g + 1) lo = m + 1; else hi = m; }
    int end = lo;
    float s = 0.f;
    const int ui = f >> 1;
    const bool hif = f & 1;
    for (int r = start + half; r < end; r += 2) {
        unsigned int u = xp[(size_t)r * 64 + ui];
        s += hif ? bf16_hi(u) : bf16_lo(u);
    }
    __shared__ float red[256];
    __shared__ float pooled[D];
    red[threadIdx.x] = s;
    __syncthreads();
    if (half == 0) {
        float tot = red[f] + red[f + 128];
        float c = (float)(end - start);
        pooled[f] = tot / fmaxf(c, 1.0f);
    }
    __syncthreads();
    int t = threadIdx.x;
    if (t < H) {
        float z = bc[t];
        for (int k = 0; k < D; k++) z = fmaf(pooled[k], Wc[k * H + t], z);
        z = fmaxf(z, 0.f);
        float v = z * Wo[t];
        for (int off = 32; off > 0; off >>= 1) v += __shfl_down(v, off);
        if (t == 0) out[g] = v + bo[0];
    }
}

// ---------- Orchestration ----------

extern "C" void kernel_launch(void* const* d_in, const int* in_sizes, int n_in,
                              void* d_out, int out_size, void* d_ws, size_t ws_size,
                              hipStream_t stream) {
    const float* x     = (const float*)d_in[0];
    const int*   ei    = (const int*)d_in[1];
    const int*   batch = (const int*)d_in[2];
    const float* W1 = (const float*)d_in[3];
    const float* b1 = (const float*)d_in[4];
    const float* W2 = (const float*)d_in[5];
    const float* b2 = (const float*)d_in[6];
    const float* W3 = (const float*)d_in[7];
    const float* b3 = (const float*)d_in[8];
    const float* Wc = (const float*)d_in[9];
    const float* bc = (const float*)d_in[10];
    const float* Wo = (const float*)d_in[11];
    const float* bo = (const float*)d_in[12];

    const int n = in_sizes[0] / D;
    const int E = in_sizes[1] / 2;
    const int G = out_size;

    char* ws = (char*)d_ws;
    size_t off = 0;
    auto alloc = [&](size_t bytes) -> void* {
        void* p = ws + off;
        off = (off + bytes + 255) & ~(size_t)255;
        return p;
    };
    int*   cnt     = (int*)alloc((size_t)n * 4 + 4096);
    int*   state   = cnt + n;                       // scan lookback state
    int*   rowptr  = (int*)alloc((size_t)(n + 1) * 4);
    float* dinv    = (float*)alloc((size_t)n * 4);
    int*   rank    = (int*)alloc((size_t)E * 4);
    int*   csr_src = (int*)alloc((size_t)E * 4 + 256);
    unsigned int* hb = (unsigned int*)alloc((size_t)n * (D / 2) * 4);  // packed bf16 gemm out
    unsigned int* xb = (unsigned int*)alloc((size_t)n * (D / 2) * 4);  // packed bf16 agg out
    (void)ws_size; (void)n_in;

    hipMemsetAsync(cnt, 0, (size_t)n * 4 + 4096, stream);

    const int nb = (n + 255) / 256;
    const int gemm_blocks = (n + 63) / 64;
    const int p1_blocks   = (E + 255) / 256;
    const int p2_blocks   = (E + 511) / 512;
    const int agg_blocks  = (n + 7) / 8;            // 2 nodes/wave, 4 waves/block

    // gemm1 (unscaled out, indep of CSR) overlapped with pass1 rank/histogram
    fat1_k<<<gemm_blocks + p1_blocks, 256, 0, stream>>>(
        x, W1, hb, n, gemm_blocks, ei, E, cnt, rank);

    scan_k<<<nb, 256, 0, stream>>>(cnt, n, state, rowptr, dinv);
    pass2_k<<<p2_blocks, 256, 0, stream>>>(ei, E, rank, rowptr, csr_src);

    // layer 1: per-edge dinv[s] (hb unscaled)
    agg_k<false><<<agg_blocks, 256, 0, stream>>>(hb, dinv, rowptr, csr_src, b1, xb, n);
    // layers 2,3: pre-scaled hb
    gemm_k<<<gemm_blocks, 256, 0, stream>>>(xb, W2, dinv, hb, n);
    agg_k<true><<<agg_blocks, 256, 0, stream>>>(hb, dinv, rowptr, csr_src, b2, xb, n);
    gemm_k<<<gemm_blocks, 256, 0, stream>>>(xb, W3, dinv, hb, n);
    agg_k<true><<<agg_blocks, 256, 0, stream>>>(hb, dinv, rowptr, csr_src, b3, xb, n);

    poolcls_k<<<G, 256, 0, stream>>>(xb, batch, n, Wc, bc, Wo, bo, (float*)d_out);
}

// Round 10
// 338.834 us; speedup vs baseline: 1.1273x; 1.0828x over previous
//
#include <hip/hip_runtime.h>

#define D 128   // feature dim
#define H 64    // hidden dim of classifier

typedef __attribute__((ext_vector_type(8))) short bf16x8;
typedef __attribute__((ext_vector_type(4))) float f32x4;

// ---------- bf16 helpers (bit-level, RNE) ----------

__device__ __forceinline__ unsigned int bf16_rne(float f) {
    unsigned int u = __float_as_uint(f);
    u += 0x7fffu + ((u >> 16) & 1u);
    return u >> 16;
}
__device__ __forceinline__ unsigned int pack_bf16(float a, float b) {
    return bf16_rne(a) | (bf16_rne(b) << 16);
}
__device__ __forceinline__ float bf16_lo(unsigned int u) { return __uint_as_float(u << 16); }
__device__ __forceinline__ float bf16_hi(unsigned int u) { return __uint_as_float(u & 0xffff0000u); }
__device__ __forceinline__ float bf16_val(unsigned int h) { return __uint_as_float(h << 16); }

__device__ __forceinline__ bf16x8 as_bf16x8(uint4 u) {
    union { uint4 u; bf16x8 b; } x; x.u = u; return x.b;
}

// ---------- W prep: fragment-ordered double-bf16 (Wh + Wl ≈ W to ~16 mantissa bits) ----------
// For mfma_f32_16x16x32_bf16 B-operand: lane l needs W[kc*32+quad*8+j][c*16+(l&15)], j=0..7.
// Layout: frag[((c*4+kc)*64 + lane)*4 + d] holds j=2d (lo16), 2d+1 (hi16).
// grid: 16 blocks x 256 -> blocks 0-7: W2, 8-15: W3 (2048 threads per W).

static __global__ void wprep_k(const float* __restrict__ W2, const float* __restrict__ W3,
                               unsigned int* __restrict__ Bh2, unsigned int* __restrict__ Bl2,
                               unsigned int* __restrict__ Bh3, unsigned int* __restrict__ Bl3) {
    const int wsel = blockIdx.x >> 3;
    const float* W = wsel ? W3 : W2;
    unsigned int* Bh = wsel ? Bh3 : Bh2;
    unsigned int* Bl = wsel ? Bl3 : Bl2;
    int tt = (blockIdx.x & 7) * 256 + threadIdx.x;   // 0..2047
    int lane = tt & 63, kc = (tt >> 6) & 3, c = tt >> 8;
    int m = lane & 15, quad = lane >> 4;
    int col = c * 16 + m;
    int k0 = kc * 32 + quad * 8;
    unsigned int h4[4], l4[4];
#pragma unroll
    for (int dd = 0; dd < 4; dd++) {
        float w0 = W[(k0 + 2 * dd) * D + col];
        float w1 = W[(k0 + 2 * dd + 1) * D + col];
        unsigned int h0 = bf16_rne(w0), h1 = bf16_rne(w1);
        unsigned int L0 = bf16_rne(w0 - bf16_val(h0));
        unsigned int L1 = bf16_rne(w1 - bf16_val(h1));
        h4[dd] = h0 | (h1 << 16);
        l4[dd] = L0 | (L1 << 16);
    }
    int base = ((c * 4 + kc) * 64 + lane) * 4;
    *(uint4*)&Bh[base] = make_uint4(h4[0], h4[1], h4[2], h4[3]);
    *(uint4*)&Bl[base] = make_uint4(l4[0], l4[1], l4[2], l4[3]);
}

// ---------- FAT: gemm layer-1 (fp32 x @ W1 -> UNSCALED bf16) ∥ CSR pass1 ----------
// r7 structure (segregated ranges; measured ~10 us real overlap).

static __global__ __launch_bounds__(256) void fat1_k(
        const float* __restrict__ x, const float* __restrict__ W,
        unsigned int* __restrict__ hb, int n, int gb,
        const int* __restrict__ ei, int E,
        int* __restrict__ cnt, int* __restrict__ rank) {
    __shared__ float Ws[32 * D];     // 16 KB
    __shared__ float xT[32 * 64];    //  8 KB
    const int tid = threadIdx.x;
    if ((int)blockIdx.x >= gb) {     // ---- pass1 ----
        int e = ((int)blockIdx.x - gb) * 256 + tid;
        if (e < E) rank[e] = atomicAdd(&cnt[ei[E + e]], 1);
        return;
    }
    // ---- gemm1 ----
    const int row0 = blockIdx.x * 64;
    const int tx = tid & 31;
    const int ty = tid >> 5;
    const int sr = tid & 63;
    const int sk = (tid >> 6) * 4;
    const int gr = row0 + sr;

    float acc[8][4];
#pragma unroll
    for (int r = 0; r < 8; r++)
#pragma unroll
        for (int c = 0; c < 4; c++) acc[r][c] = 0.f;

    for (int kc = 0; kc < D; kc += 32) {
        float4 wreg[4];
#pragma unroll
        for (int i = 0; i < 4; i++)
            wreg[i] = ((const float4*)(W + kc * D))[tid + 256 * i];
        float4 v0 = make_float4(0.f, 0.f, 0.f, 0.f), v1 = v0;
        if (gr < n) {
            v0 = *(const float4*)&x[(size_t)gr * D + kc + sk];
            v1 = *(const float4*)&x[(size_t)gr * D + kc + sk + 16];
        }
        __syncthreads();
#pragma unroll
        for (int i = 0; i < 4; i++)
            ((float4*)Ws)[tid + 256 * i] = wreg[i];
        xT[(sk + 0) * 64 + sr] = v0.x;
        xT[(sk + 1) * 64 + sr] = v0.y;
        xT[(sk + 2) * 64 + sr] = v0.z;
        xT[(sk + 3) * 64 + sr] = v0.w;
        xT[(sk + 16) * 64 + sr] = v1.x;
        xT[(sk + 17) * 64 + sr] = v1.y;
        xT[(sk + 18) * 64 + sr] = v1.z;
        xT[(sk + 19) * 64 + sr] = v1.w;
        __syncthreads();
#pragma unroll 8
        for (int k = 0; k < 32; k++) {
            float4 w  = *(const float4*)&Ws[k * D + tx * 4];
            float4 xa = *(const float4*)&xT[k * 64 + ty * 8];
            float4 xb = *(const float4*)&xT[k * 64 + ty * 8 + 4];
            acc[0][0] = fmaf(xa.x, w.x, acc[0][0]); acc[0][1] = fmaf(xa.x, w.y, acc[0][1]);
            acc[0][2] = fmaf(xa.x, w.z, acc[0][2]); acc[0][3] = fmaf(xa.x, w.w, acc[0][3]);
            acc[1][0] = fmaf(xa.y, w.x, acc[1][0]); acc[1][1] = fmaf(xa.y, w.y, acc[1][1]);
            acc[1][2] = fmaf(xa.y, w.z, acc[1][2]); acc[1][3] = fmaf(xa.y, w.w, acc[1][3]);
            acc[2][0] = fmaf(xa.z, w.x, acc[2][0]); acc[2][1] = fmaf(xa.z, w.y, acc[2][1]);
            acc[2][2] = fmaf(xa.z, w.z, acc[2][2]); acc[2][3] = fmaf(xa.z, w.w, acc[2][3]);
            acc[3][0] = fmaf(xa.w, w.x, acc[3][0]); acc[3][1] = fmaf(xa.w, w.y, acc[3][1]);
            acc[3][2] = fmaf(xa.w, w.z, acc[3][2]); acc[3][3] = fmaf(xa.w, w.w, acc[3][3]);
            acc[4][0] = fmaf(xb.x, w.x, acc[4][0]); acc[4][1] = fmaf(xb.x, w.y, acc[4][1]);
            acc[4][2] = fmaf(xb.x, w.z, acc[4][2]); acc[4][3] = fmaf(xb.x, w.w, acc[4][3]);
            acc[5][0] = fmaf(xb.y, w.x, acc[5][0]); acc[5][1] = fmaf(xb.y, w.y, acc[5][1]);
            acc[5][2] = fmaf(xb.y, w.z, acc[5][2]); acc[5][3] = fmaf(xb.y, w.w, acc[5][3]);
            acc[6][0] = fmaf(xb.z, w.x, acc[6][0]); acc[6][1] = fmaf(xb.z, w.y, acc[6][1]);
            acc[6][2] = fmaf(xb.z, w.z, acc[6][2]); acc[6][3] = fmaf(xb.z, w.w, acc[6][3]);
            acc[7][0] = fmaf(xb.w, w.x, acc[7][0]); acc[7][1] = fmaf(xb.w, w.y, acc[7][1]);
            acc[7][2] = fmaf(xb.w, w.z, acc[7][2]); acc[7][3] = fmaf(xb.w, w.w, acc[7][3]);
        }
    }
#pragma unroll
    for (int r = 0; r < 8; r++) {
        int grr = row0 + ty * 8 + r;
        if (grr < n) {
            uint2 p;
            p.x = pack_bf16(acc[r][0], acc[r][1]);
            p.y = pack_bf16(acc[r][2], acc[r][3]);
            *(uint2*)&hb[(size_t)grr * (D / 2) + tx * 2] = p;
        }
    }
}

// ---------- Single-dispatch exclusive scan (decoupled lookback) + dinv ----------

static __global__ __launch_bounds__(256) void scan_k(
        const int* __restrict__ cnt, int n, int* __restrict__ state,
        int* __restrict__ rowptr, float* __restrict__ dinv) {
    __shared__ int s[256];
    __shared__ int sprefix;
    const int b = blockIdx.x;
    const int i = b * 256 + threadIdx.x;
    int v = (i < n) ? cnt[i] : 0;
    if (i < n) dinv[i] = rsqrtf((float)v + 1.0f);   // +1 self loop
    s[threadIdx.x] = v;
    __syncthreads();
    for (int off = 1; off < 256; off <<= 1) {
        int t = ((int)threadIdx.x >= off) ? s[threadIdx.x - off] : 0;
        __syncthreads();
        s[threadIdx.x] += t;
        __syncthreads();
    }
    int incl = s[threadIdx.x];
    int total = s[255];
    if (threadIdx.x == 0) {
        if (b == 0) {
            atomicExch(&state[0], (total << 2) | 2);
            sprefix = 0;
        } else {
            atomicExch(&state[b], (total << 2) | 1);
            int run = 0;
            for (int j = b - 1; j >= 0; j--) {
                int p;
                do { p = atomicAdd(&state[j], 0); } while ((p & 3) == 0);
                run += (p >> 2);
                if ((p & 3) == 2) break;
            }
            atomicExch(&state[b], ((run + total) << 2) | 2);
            sprefix = run;
        }
    }
    __syncthreads();
    int pre = sprefix;
    if (i < n) {
        rowptr[i] = pre + incl - v;
        if (i == n - 1) rowptr[n] = pre + incl;
    }
}

// ---------- pass2: no-atomic scatter, 2 edges/thread ----------

static __global__ void pass2_k(const int* __restrict__ ei, int E,
                               const int* __restrict__ rank,
                               const int* __restrict__ rowptr,
                               int* __restrict__ csr_src) {
    int e0 = (blockIdx.x * blockDim.x + threadIdx.x) * 2;
    if (e0 + 1 < E) {
        int2 s2 = *(const int2*)&ei[e0];
        int2 d2 = *(const int2*)&ei[E + e0];
        int2 r2 = *(const int2*)&rank[e0];
        csr_src[rowptr[d2.x] + r2.x] = s2.x;
        csr_src[rowptr[d2.y] + r2.y] = s2.y;
    } else if (e0 < E) {
        csr_src[rowptr[ei[E + e0]] + rank[e0]] = ei[e0];
    }
}

// ---------- Aggregation + bias + relu: 2 nodes per wave (r9) ----------

template <bool SCALED>
static __global__ __launch_bounds__(256) void agg_k(const unsigned int* __restrict__ hb,
                                                    const float* __restrict__ dinv,
                                                    const int* __restrict__ rowptr,
                                                    const int* __restrict__ csr,
                                                    const float* __restrict__ b,
                                                    unsigned int* __restrict__ outp, int n) {
    int nodeA = blockIdx.x * 8 + ((threadIdx.x >> 6) << 1);
    nodeA = __builtin_amdgcn_readfirstlane(nodeA);
    if (nodeA >= n) return;
    const int nodeB = nodeA + 1;
    const bool hasB = nodeB < n;
    const int lane = threadIdx.x & 63;
    const int half = lane >> 5;
    const int l = lane & 31;

    const int begA = rowptr[nodeA];
    const int endA = rowptr[nodeA + 1];
    const int begB = hasB ? endA : 0;
    const int endB = hasB ? rowptr[nodeB + 1] : 0;
    const int safeA = (endA > begA) ? endA - 1 : 0;
    const int safeB = (endB > begB) ? endB - 1 : 0;
    const int degA = endA - begA, degB = endB - begB;
    int nbat = (degA > degB ? degA : degB);
    nbat = (nbat + 7) >> 3;

    const int myEnd = half ? endB : endA;
    float a0 = 0.f, a1 = 0.f, a2 = 0.f, a3 = 0.f;
    for (int t = 0; t < nbat; t++) {
        int s[8];
        float w[8];
#pragma unroll
        for (int i = 0; i < 8; i++) {
            int eA = begA + t * 8 + i; int ecA = (eA < endA) ? eA : safeA;
            int eB = begB + t * 8 + i; int ecB = (eB < endB) ? eB : safeB;
            int sA = csr[ecA];
            int sB = csr[ecB];
            s[i] = half ? sB : sA;
            bool live = (half ? eB : eA) < myEnd;
            if constexpr (SCALED) {
                w[i] = live ? 1.0f : 0.0f;
            } else {
                float dA = dinv[sA];
                float dB = dinv[sB];
                w[i] = live ? (half ? dB : dA) : 0.0f;
            }
        }
#pragma unroll
        for (int i = 0; i < 8; i++) {
            uint2 v = *(const uint2*)&hb[(size_t)s[i] * 64 + l * 2];
            a0 = fmaf(w[i], bf16_lo(v.x), a0);
            a1 = fmaf(w[i], bf16_hi(v.x), a1);
            a2 = fmaf(w[i], bf16_lo(v.y), a2);
            a3 = fmaf(w[i], bf16_hi(v.y), a3);
        }
    }
    const int node = half ? nodeB : nodeA;
    const float dA = dinv[nodeA];
    const float dB = hasB ? dinv[nodeB] : 0.f;
    const float di = half ? dB : dA;
    uint2 hv = *(const uint2*)&hb[(size_t)(hasB ? node : nodeA) * 64 + l * 2];
    if constexpr (SCALED) {
        a0 += bf16_lo(hv.x); a1 += bf16_hi(hv.x);
        a2 += bf16_lo(hv.y); a3 += bf16_hi(hv.y);
    } else {
        a0 = fmaf(di, bf16_lo(hv.x), a0); a1 = fmaf(di, bf16_hi(hv.x), a1);
        a2 = fmaf(di, bf16_lo(hv.y), a2); a3 = fmaf(di, bf16_hi(hv.y), a3);
    }
    float4 bb = *(const float4*)&b[l * 4];
    float o0 = fmaxf(fmaf(di, a0, bb.x), 0.f);
    float o1 = fmaxf(fmaf(di, a1, bb.y), 0.f);
    float o2 = fmaxf(fmaf(di, a2, bb.z), 0.f);
    float o3 = fmaxf(fmaf(di, a3, bb.w), 0.f);
    if (half == 0 || hasB) {
        uint2 p;
        p.x = pack_bf16(o0, o1);
        p.y = pack_bf16(o2, o3);
        *(uint2*)&outp[(size_t)node * 64 + l * 2] = p;
    }
}

// ---------- MFMA GEMM layers 2/3: hb = bf16( dinv[row] * (xpacked @ W) ) ----------
// LDS-free. 4 waves x 16 rows; A from packed-bf16 x (A[m=lane&15][k=quad*8+j]);
// B from fragment-ordered double-bf16 prep (L2-hot); 2 mfma per K-chunk (Wh + Wl).
// C layout: col = lane&15, row = quad*4 + reg. Stores u16, 32 B contiguous per quad-row.

static __global__ __launch_bounds__(256) void gemm_mfma_k(
        const unsigned int* __restrict__ xp,
        const unsigned int* __restrict__ Bh, const unsigned int* __restrict__ Bl,
        const float* __restrict__ dinv, unsigned int* __restrict__ hb, int n) {
    const int tid = threadIdx.x;
    const int w = tid >> 6;
    const int lane = tid & 63;
    const int m = lane & 15, quad = lane >> 4;
    const int arow = blockIdx.x * 64 + w * 16 + m;        // A row for this lane
    const bool rok = arow < n;

    uint4 A[4];
#pragma unroll
    for (int kc = 0; kc < 4; kc++)
        A[kc] = rok ? *(const uint4*)&xp[(size_t)arow * 64 + kc * 16 + quad * 4]
                    : make_uint4(0u, 0u, 0u, 0u);

    const int erow0 = blockIdx.x * 64 + w * 16 + quad * 4;  // C rows for regs 0..3
    float dvr[4];
#pragma unroll
    for (int r = 0; r < 4; r++)
        dvr[r] = (erow0 + r < n) ? dinv[erow0 + r] : 0.f;

    unsigned short* out = (unsigned short*)hb;
#pragma unroll
    for (int c = 0; c < 8; c++) {
        f32x4 acc = {0.f, 0.f, 0.f, 0.f};
#pragma unroll
        for (int kc = 0; kc < 4; kc++) {
            int base = ((c * 4 + kc) * 64 + lane) * 4;
            uint4 bh = *(const uint4*)&Bh[base];
            uint4 bl = *(const uint4*)&Bl[base];
            acc = __builtin_amdgcn_mfma_f32_16x16x32_bf16(as_bf16x8(A[kc]), as_bf16x8(bh), acc, 0, 0, 0);
            acc = __builtin_amdgcn_mfma_f32_16x16x32_bf16(as_bf16x8(A[kc]), as_bf16x8(bl), acc, 0, 0, 0);
        }
        int col = c * 16 + m;
#pragma unroll
        for (int r = 0; r < 4; r++) {
            int rr = erow0 + r;
            if (rr < n)
                out[(size_t)rr * D + col] = (unsigned short)bf16_rne(acc[r] * dvr[r]);
        }
    }
}

// ---------- Fused mean-pool + classifier ----------

static __global__ __launch_bounds__(256) void poolcls_k(const unsigned int* __restrict__ xp,
                                                        const int* __restrict__ batch, int n,
                                                        const float* __restrict__ Wc,
                                                        const float* __restrict__ bc,
                                                        const float* __restrict__ Wo,
                                                        const float* __restrict__ bo,
                                                        float* __restrict__ out) {
    int g = blockIdx.x;
    int f = threadIdx.x & 127;
    int half = threadIdx.x >> 7;
    int lo = 0, hi = n;
    while (lo < hi) { int m = (lo + hi) >> 1; if (batch[m] < g) lo = m + 1; else hi = m; }
    int start = lo;
    hi = n;
    while (lo < hi) { int m = (lo + hi) >> 1; if (batch[m] < g + 1) lo = m + 1; else hi = m; }
    int end = lo;
    float s = 0.f;
    const int ui = f >> 1;
    const bool hif = f & 1;
    for (int r = start + half; r < end; r += 2) {
        unsigned int u = xp[(size_t)r * 64 + ui];
        s += hif ? bf16_hi(u) : bf16_lo(u);
    }
    __shared__ float red[256];
    __shared__ float pooled[D];
    red[threadIdx.x] = s;
    __syncthreads();
    if (half == 0) {
        float tot = red[f] + red[f + 128];
        float c = (float)(end - start);
        pooled[f] = tot / fmaxf(c, 1.0f);
    }
    __syncthreads();
    int t = threadIdx.x;
    if (t < H) {
        float z = bc[t];
        for (int k = 0; k < D; k++) z = fmaf(pooled[k], Wc[k * H + t], z);
        z = fmaxf(z, 0.f);
        float v = z * Wo[t];
        for (int off = 32; off > 0; off >>= 1) v += __shfl_down(v, off);
        if (t == 0) out[g] = v + bo[0];
    }
}

// ---------- Orchestration ----------

extern "C" void kernel_launch(void* const* d_in, const int* in_sizes, int n_in,
                              void* d_out, int out_size, void* d_ws, size_t ws_size,
                              hipStream_t stream) {
    const float* x     = (const float*)d_in[0];
    const int*   ei    = (const int*)d_in[1];
    const int*   batch = (const int*)d_in[2];
    const float* W1 = (const float*)d_in[3];
    const float* b1 = (const float*)d_in[4];
    const float* W2 = (const float*)d_in[5];
    const float* b2 = (const float*)d_in[6];
    const float* W3 = (const float*)d_in[7];
    const float* b3 = (const float*)d_in[8];
    const float* Wc = (const float*)d_in[9];
    const float* bc = (const float*)d_in[10];
    const float* Wo = (const float*)d_in[11];
    const float* bo = (const float*)d_in[12];

    const int n = in_sizes[0] / D;
    const int E = in_sizes[1] / 2;
    const int G = out_size;

    char* ws = (char*)d_ws;
    size_t off = 0;
    auto alloc = [&](size_t bytes) -> void* {
        void* p = ws + off;
        off = (off + bytes + 255) & ~(size_t)255;
        return p;
    };
    int*   cnt     = (int*)alloc((size_t)n * 4 + 4096);
    int*   state   = cnt + n;                       // scan lookback state
    int*   rowptr  = (int*)alloc((size_t)(n + 1) * 4);
    float* dinv    = (float*)alloc((size_t)n * 4);
    int*   rank    = (int*)alloc((size_t)E * 4);
    int*   csr_src = (int*)alloc((size_t)E * 4 + 256);
    unsigned int* hb = (unsigned int*)alloc((size_t)n * (D / 2) * 4);  // packed bf16 gemm out
    unsigned int* xb = (unsigned int*)alloc((size_t)n * (D / 2) * 4);  // packed bf16 agg out
    unsigned int* Bh2 = (unsigned int*)alloc(32 * 1024);
    unsigned int* Bl2 = (unsigned int*)alloc(32 * 1024);
    unsigned int* Bh3 = (unsigned int*)alloc(32 * 1024);
    unsigned int* Bl3 = (unsigned int*)alloc(32 * 1024);
    (void)ws_size; (void)n_in;

    hipMemsetAsync(cnt, 0, (size_t)n * 4 + 4096, stream);

    const int nb = (n + 255) / 256;
    const int gemm_blocks = (n + 63) / 64;
    const int p1_blocks   = (E + 255) / 256;
    const int p2_blocks   = (E + 511) / 512;
    const int agg_blocks  = (n + 7) / 8;            // 2 nodes/wave, 4 waves/block

    wprep_k<<<16, 256, 0, stream>>>(W2, W3, Bh2, Bl2, Bh3, Bl3);

    // gemm1 (unscaled out, indep of CSR) overlapped with pass1 rank/histogram
    fat1_k<<<gemm_blocks + p1_blocks, 256, 0, stream>>>(
        x, W1, hb, n, gemm_blocks, ei, E, cnt, rank);

    scan_k<<<nb, 256, 0, stream>>>(cnt, n, state, rowptr, dinv);
    pass2_k<<<p2_blocks, 256, 0, stream>>>(ei, E, rank, rowptr, csr_src);

    // layer 1: per-edge dinv[s] (hb unscaled)
    agg_k<false><<<agg_blocks, 256, 0, stream>>>(hb, dinv, rowptr, csr_src, b1, xb, n);
    // layers 2,3: MFMA gemm (pre-scaled epilogue) + pre-scaled agg
    gemm_mfma_k<<<gemm_blocks, 256, 0, stream>>>(xb, Bh2, Bl2, dinv, hb, n);
    agg_k<true><<<agg_blocks, 256, 0, stream>>>(hb, dinv, rowptr, csr_src, b2, xb, n);
    gemm_mfma_k<<<gemm_blocks, 256, 0, stream>>>(xb, Bh3, Bl3, dinv, hb, n);
    agg_k<true><<<agg_blocks, 256, 0, stream>>>(hb, dinv, rowptr, csr_src, b3, xb, n);

    poolcls_k<<<G, 256, 0, stream>>>(xb, batch, n, Wc, bc, Wo, bo, (float*)d_out);
}